// Round 13
// baseline (180.609 us; speedup 1.0000x reference)
//
#include <hip/hip_runtime.h>
#include <stdint.h>

#define DIM 768
#define NHEADS 12
#define HDIM 64
#define DHALF 32
#define NTOK 2048
#define QKVN 2304
#define LOG2E 1.44269504088896340736f

typedef unsigned short u16;
typedef unsigned int u32;
typedef __bf16 bf16x8 __attribute__((ext_vector_type(8)));
typedef short s16x8 __attribute__((ext_vector_type(8)));
typedef float f32x4 __attribute__((ext_vector_type(4)));

__device__ __forceinline__ f32x4 f4zero() { f32x4 z = {0.f, 0.f, 0.f, 0.f}; return z; }

// fp32 -> bf16 bits, round-to-nearest-even
__device__ __forceinline__ u16 f2bf(float f) {
    u32 u = __builtin_bit_cast(u32, f);
    u32 r = (u + 0x7FFFu + ((u >> 16) & 1u)) >> 16;
    return (u16)r;
}

// async global->LDS, 16B per lane. LDS dest = wave-uniform base + lane*16.
__device__ __forceinline__ void gld_lds16(void* lds, const void* g) {
    __builtin_amdgcn_global_load_lds((const __attribute__((address_space(1))) u32*)g,
                                     (__attribute__((address_space(3))) u32*)lds,
                                     16, 0, 0);
}

// ---------------------------------------------------------------------------
// fused fp32 -> bf16 cast of x, w_qkv, w_proj (one launch)
// ---------------------------------------------------------------------------
__global__ __launch_bounds__(256) void cast3_f32_to_bf16(const float* __restrict__ a, u16* __restrict__ oa, int na4,
                                                         const float* __restrict__ b, u16* __restrict__ ob, int nb4,
                                                         const float* __restrict__ c, u16* __restrict__ oc, int nc4) {
    int i = blockIdx.x * 256 + threadIdx.x;
    const float* src;
    u16* dst;
    int j = i;
    if (i < na4) { src = a; dst = oa; }
    else if (i < na4 + nb4) { src = b; dst = ob; j = i - na4; }
    else if (i < na4 + nb4 + nc4) { src = c; dst = oc; j = i - na4 - nb4; }
    else return;
    float4 v = ((const float4*)src)[j];
    u32 w0 = (u32)f2bf(v.x) | ((u32)f2bf(v.y) << 16);
    u32 w1 = (u32)f2bf(v.z) | ((u32)f2bf(v.w) << 16);
    ((uint2*)dst)[j] = make_uint2(w0, w1);
}

// ---------------------------------------------------------------------------
// proj GEMM 64x64 tiles (768 WG = 3 WG/CU balanced), dbuf gld_lds.
// C[M,N] = A[M,K]*B[N,K]^T (+bias), bf16 in, fp32 out.
// ---------------------------------------------------------------------------
__global__ __launch_bounds__(256) void gemm_bt(const u16* __restrict__ A, const u16* __restrict__ Bm,
                                               float* __restrict__ C, const float* __restrict__ bias,
                                               int M, int N, int K) {
    __shared__ __align__(16) u16 sA[2][64 * 32];
    __shared__ __align__(16) u16 sB[2][64 * 32];
    const int t = threadIdx.x;
    const int wave = t >> 6, lane = t & 63;
    const int quad = lane >> 4, l16 = lane & 15;
    const int bm = blockIdx.y * 64, bn = blockIdx.x * 64;
    const int wr = wave >> 1, wc = wave & 1;

    f32x4 acc[2][2];
#pragma unroll
    for (int i = 0; i < 2; i++)
#pragma unroll
        for (int j = 0; j < 2; j++) acc[i][j] = f4zero();

    auto stage = [&](int k0, int bi) {
        gld_lds16((char*)&sA[bi][0] + wave * 1024,
                  A + (size_t)(bm + wave * 16 + (lane >> 2)) * K + k0 + (lane & 3) * 8);
        gld_lds16((char*)&sB[bi][0] + wave * 1024,
                  Bm + (size_t)(bn + wave * 16 + (lane >> 2)) * K + k0 + (lane & 3) * 8);
    };

    stage(0, 0);
    int cur = 0;
    for (int k0 = 0; k0 < K; k0 += 32) {
        __syncthreads();  // drains DMA of buf[cur]; protects buf[cur^1] reuse
        if (k0 + 32 < K) stage(k0 + 32, cur ^ 1);
        const u16* pA = &sA[cur][0];
        const u16* pB = &sB[cur][0];
        bf16x8 af[2], bfr[2];
#pragma unroll
        for (int mb = 0; mb < 2; mb++)
            af[mb] = *(const bf16x8*)(pA + (wr * 32 + mb * 16 + l16) * 32 + quad * 8);
#pragma unroll
        for (int nb = 0; nb < 2; nb++)
            bfr[nb] = *(const bf16x8*)(pB + (wc * 32 + nb * 16 + l16) * 32 + quad * 8);
#pragma unroll
        for (int mb = 0; mb < 2; mb++)
#pragma unroll
            for (int nb = 0; nb < 2; nb++)
                acc[mb][nb] = __builtin_amdgcn_mfma_f32_16x16x32_bf16(af[mb], bfr[nb], acc[mb][nb], 0, 0, 0);
        cur ^= 1;
    }
#pragma unroll
    for (int mb = 0; mb < 2; mb++)
#pragma unroll
        for (int nb = 0; nb < 2; nb++) {
            int col = bn + wc * 32 + nb * 16 + l16;
            float bv = bias ? bias[col] : 0.f;
#pragma unroll
            for (int r = 0; r < 4; r++) {
                int row = bm + wr * 32 + mb * 16 + quad * 4 + r;
                C[(size_t)row * N + col] = acc[mb][nb][r] + bv;
            }
        }
}

// ---------------------------------------------------------------------------
// QKV-GEMM (fused RoPE + flash-layout epilogue), 128x64 tiles, 4 vertical
// waves, grid 1152 = 4.5 WG/CU. Pow2 fast path for n->(zd,yh,xw).
// ---------------------------------------------------------------------------
__global__ __launch_bounds__(256) void gemm_qkv_rope(const u16* __restrict__ A, const u16* __restrict__ Bm,
                                                     const float* __restrict__ voxel,
                                                     const float* __restrict__ theta,
                                                     const int* __restrict__ gh_p, const int* __restrict__ gw_p,
                                                     u16* __restrict__ q_s, u16* __restrict__ k_s,
                                                     u16* __restrict__ vT, int M) {
    __shared__ __align__(16) u16 sA[2][128 * 32];
    __shared__ __align__(16) u16 sB[2][64 * 32];
    const int t = threadIdx.x;
    const int wave = t >> 6, lane = t & 63;
    const int quad = lane >> 4, l16 = lane & 15;
    const int bm = blockIdx.y * 128, bn = blockIdx.x * 64;
    const int K = DIM;

    f32x4 acc[2][4];
#pragma unroll
    for (int i = 0; i < 2; i++)
#pragma unroll
        for (int j = 0; j < 4; j++) acc[i][j] = f4zero();

    auto stage = [&](int k0, int bi) {
#pragma unroll
        for (int s = 0; s < 2; ++s) {
            int ci = wave * 2 + s;  // A chunk: rows ci*16..ci*16+15
            gld_lds16((char*)&sA[bi][0] + ci * 1024,
                      A + (size_t)(bm + ci * 16 + (lane >> 2)) * K + k0 + (lane & 3) * 8);
        }
        gld_lds16((char*)&sB[bi][0] + wave * 1024,
                  Bm + (size_t)(bn + wave * 16 + (lane >> 2)) * K + k0 + (lane & 3) * 8);
    };

    stage(0, 0);
    int cur = 0;
    for (int k0 = 0; k0 < K; k0 += 32) {
        __syncthreads();
        if (k0 + 32 < K) stage(k0 + 32, cur ^ 1);
        const u16* pA = &sA[cur][0];
        const u16* pB = &sB[cur][0];
        bf16x8 af[2], bfr[4];
#pragma unroll
        for (int mb = 0; mb < 2; mb++)
            af[mb] = *(const bf16x8*)(pA + (wave * 32 + mb * 16 + l16) * 32 + quad * 8);
#pragma unroll
        for (int nb = 0; nb < 4; nb++)
            bfr[nb] = *(const bf16x8*)(pB + (nb * 16 + l16) * 32 + quad * 8);
#pragma unroll
        for (int mb = 0; mb < 2; mb++)
#pragma unroll
            for (int nb = 0; nb < 4; nb++)
                acc[mb][nb] = __builtin_amdgcn_mfma_f32_16x16x32_bf16(af[mb], bfr[nb], acc[mb][nb], 0, 0, 0);
        cur ^= 1;
    }

    // ---------------- fused epilogue ----------------
    const int col0 = bn;                     // 64-col block = one head window
    const int typ = col0 / DIM;              // 0=Q, 1=K, 2=V (block-uniform)
    const int h = (col0 % DIM) >> 6;
    const int b = bm / NTOK;
    const int n0 = (bm % NTOK) + wave * 32;  // wave's token base (mult of 32)
    const size_t bh = (size_t)b * NHEADS + h;

    if (typ == 2) {
        // ---- V: register-local fragment-major pack (one chunk per wave) ----
        int chunk = ((bm % NTOK) >> 5) + wave;
        u16* base = vT + ((size_t)bh * 64 + chunk) * 2048;
#pragma unroll
        for (int nb = 0; nb < 4; nb++) {
            u32 w0 = (u32)f2bf(acc[0][nb][0]) | ((u32)f2bf(acc[0][nb][1]) << 16);
            u32 w1 = (u32)f2bf(acc[0][nb][2]) | ((u32)f2bf(acc[0][nb][3]) << 16);
            u32 w2 = (u32)f2bf(acc[1][nb][0]) | ((u32)f2bf(acc[1][nb][1]) << 16);
            u32 w3 = (u32)f2bf(acc[1][nb][2]) | ((u32)f2bf(acc[1][nb][3]) << 16);
            *(uint4*)(base + nb * 512 + lane * 8) = make_uint4(w0, w1, w2, w3);
        }
    } else {
        // ---- Q/K: in-register RoPE ----
        const int gh = *gh_p, gw = *gw_p;
        const bool p2 = ((gw & (gw - 1)) == 0) && ((gh & (gh - 1)) == 0);
        const int wsh = 31 - __builtin_clz(gw), hsh = 31 - __builtin_clz(gh);
        const float qsc = (typ == 0) ? 0.125f * LOG2E : 1.0f;
        const float th0 = theta[h * DHALF + l16];
        const float th1 = theta[h * DHALF + 16 + l16];
        const int ax0 = l16 % 3, ax1 = (16 + l16) % 3;
        const float vx0 = voxel[ax0], vx1 = voxel[ax1];
#pragma unroll
        for (int mb = 0; mb < 2; mb++)
#pragma unroll
            for (int r = 0; r < 4; r++) {
                int n = n0 + mb * 16 + quad * 4 + r;
                int xw, yh, zd;
                if (p2) {  // pow2 grid (the actual case: 8x16x16): 3 ops
                    xw = n & (gw - 1);
                    int rem = n >> wsh;
                    yh = rem & (gh - 1);
                    zd = rem >> hsh;
                } else {   // generic path, branched around at runtime
                    xw = n % gw;
                    int rem = n / gw;
                    yh = rem % gh;
                    zd = rem / gh;
                }
                float c0 = (float)(ax0 == 0 ? zd : (ax0 == 1 ? yh : xw)) * vx0;
                float c1 = (float)(ax1 == 0 ? zd : (ax1 == 1 ? yh : xw)) * vx1;
                float s0, co0, s1, co1;
                __sincosf(c0 * th0, &s0, &co0);
                __sincosf(c1 * th1, &s1, &co1);
                float t1a = acc[mb][0][r], t2a = acc[mb][2][r];
                float o1a = (t1a * co0 - t2a * s0) * qsc, o2a = (t1a * s0 + t2a * co0) * qsc;
                float t1b = acc[mb][1][r], t2b = acc[mb][3][r];
                float o1b = (t1b * co1 - t2b * s1) * qsc, o2b = (t1b * s1 + t2b * co1) * qsc;
                if (typ == 0) {
                    u16* dq = q_s + (bh * NTOK + n) * HDIM;
                    dq[l16] = f2bf(o1a);
                    dq[l16 + DHALF] = f2bf(o2a);
                    dq[16 + l16] = f2bf(o1b);
                    dq[48 + l16] = f2bf(o2b);
                } else {
                    // fragment-major K (matches flash's kf read pattern)
                    int gm = wave * 2 + mb;
                    int tile_i = ((bm % NTOK) >> 6) + (gm >> 2);
                    int g = gm & 3;
                    int k16 = quad * 4 + r;
                    size_t baseo = bh * (size_t)NTOK * HDIM + (size_t)tile_i * 4096 + g * 1024;
                    int j = l16 & 7;
                    size_t oa = baseo + (size_t)(((l16 >> 3) * 16 + k16) * 8 + j);
                    size_t ob = baseo + (size_t)((((2 + (l16 >> 3)) * 16) + k16) * 8 + j);
                    k_s[oa] = f2bf(o1a);
                    k_s[oa + 512] = f2bf(o2a);
                    k_s[ob] = f2bf(o1b);
                    k_s[ob + 512] = f2bf(o2b);
                }
            }
    }
}

// ---------------------------------------------------------------------------
// Flash attention v15 = v14 (V direct from L2) + ONE-ITERATION-AHEAD V
// REGISTER PREFETCH. v14's regression mechanism (from counters): V loads
// were issued AFTER the stage DMA; vmcnt is in-order, so waiting for V
// before PV emitted vmcnt(0) and drained the next-tile K staging -> prefetch
// destroyed (VALUBusy 60->54). v15: V for tile kt+1 is loaded into bvn[]
// DURING tile kt's compute; the loads ride in flight across ~2000 cyc and
// are drained for free by the next barrier's vmcnt(0). PV consumes bv[]
// (loaded one iteration earlier) with ZERO waits, and stage-DMA ordering is
// irrelevant. +32 VGPR (bv+bvn); LDS 16KB; barrier cadence/setprio/epilogue
// identical to R7 (51.1us proven).
// ---------------------------------------------------------------------------
__global__ __launch_bounds__(256) void flash_attn(const u16* __restrict__ Q, const u16* __restrict__ Kp,
                                                  const u16* __restrict__ Vp, u16* __restrict__ Out, int NBH) {
    int i = blockIdx.x;
    int bh_i = i % NBH;   // all of a bh's WGs land on XCD bh%8 (24%8==0)
    int qt = i / NBH;     // 0..31
    int b = bh_i / NHEADS, h = bh_i % NHEADS;
    int t = threadIdx.x, wave = t >> 6, lane = t & 63, quad = lane >> 4, l16 = lane & 15;
    size_t bh = (size_t)b * NHEADS + h;
    const u16* Qb = Q + bh * NTOK * HDIM;
    const u16* Kb = Kp + bh * NTOK * HDIM;  // frag-major 4096-elem tiles
    const u16* Vb = Vp + bh * NTOK * HDIM;  // frag-major: 2 chunks x 2048 per tile

    __shared__ __align__(16) u16 smem[2][4096];  // [buf][K 4096] = 16KB (V not staged)

    const int q0 = qt * 64 + wave * 16;  // 16 q-rows per wave
    bf16x8 qf[2];
#pragma unroll
    for (int kc = 0; kc < 2; kc++)
        qf[kc] = *(const bf16x8*)(Qb + (size_t)(q0 + l16) * HDIM + kc * 32 + quad * 8);

    // ones B-frag: col 0 accumulates the P row-sum
    s16x8 ov;
#pragma unroll
    for (int j = 0; j < 8; j++) ov[j] = (l16 == 0) ? (short)0x3F80 : (short)0;

    f32x4 o[5];
#pragma unroll
    for (int db = 0; db < 5; db++) o[db] = f4zero();

    // stage 8KB K of tile kt into buffer bi (2 x 1KB DMA per wave)
    auto stage = [&](int kt, int bi) {
        const u16* Kg = Kb + (size_t)kt * 4096;
        u16* buf = &smem[bi][0];
#pragma unroll
        for (int s = 0; s < 2; s++)
            gld_lds16(buf + (wave * 2 + s) * 512, Kg + (wave * 2 + s) * 512 + lane * 8);
    };

    // V register prefetch: tile kt's fragments, issued one iteration early
    s16x8 bv[2][4], bvn[2][4];
#pragma unroll
    for (int c = 0; c < 2; ++c)
#pragma unroll
        for (int db = 0; db < 4; db++)
            bvn[c][db] = *(const s16x8*)(Vb + c * 2048 + db * 512 + lane * 8);

    stage(0, 0);
    int cur = 0;
    for (int kt = 0; kt < NTOK / 64; ++kt) {
        __syncthreads();  // drains K-DMA of buf[cur] AND bvn loads of tile kt
        if (kt + 1 < NTOK / 64) stage(kt + 1, cur ^ 1);
        // rotate prefetched V into bv; issue next tile's V loads (they fly
        // across this iteration's whole compute phase)
#pragma unroll
        for (int c = 0; c < 2; ++c)
#pragma unroll
            for (int db = 0; db < 4; db++)
                bv[c][db] = bvn[c][db];
        if (kt + 1 < NTOK / 64) {
            const u16* Vn = Vb + (size_t)(kt + 1) * 4096;
#pragma unroll
            for (int c = 0; c < 2; ++c)
#pragma unroll
                for (int db = 0; db < 4; db++)
                    bvn[c][db] = *(const s16x8*)(Vn + c * 2048 + db * 512 + lane * 8);
        }
        const u16* sK = &smem[cur][0];
#pragma unroll
        for (int c = 0; c < 2; ++c) {
            bf16x8 kf[2][2];
#pragma unroll
            for (int kb2 = 0; kb2 < 2; kb2++)
#pragma unroll
                for (int kc = 0; kc < 2; kc++)
                    kf[kb2][kc] = *(const bf16x8*)(sK + ((c * 2 + kb2) * 2 + kc) * 512 + lane * 8);
            f32x4 st0, st1;
            __builtin_amdgcn_s_setprio(1);
            {
                f32x4 z = f4zero();
                z = __builtin_amdgcn_mfma_f32_16x16x32_bf16(kf[0][0], qf[0], z, 0, 0, 0);
                st0 = __builtin_amdgcn_mfma_f32_16x16x32_bf16(kf[0][1], qf[1], z, 0, 0, 0);
                f32x4 z2 = f4zero();
                z2 = __builtin_amdgcn_mfma_f32_16x16x32_bf16(kf[1][0], qf[0], z2, 0, 0, 0);
                st1 = __builtin_amdgcn_mfma_f32_16x16x32_bf16(kf[1][1], qf[1], z2, 0, 0, 0);
            }
            __builtin_amdgcn_s_setprio(0);
            bf16x8 pb;
#pragma unroll
            for (int r = 0; r < 4; r++) {
                pb[r] = (__bf16)__builtin_exp2f(st0[r]);
                pb[r + 4] = (__bf16)__builtin_exp2f(st1[r]);
            }
            __builtin_amdgcn_s_setprio(1);
#pragma unroll
            for (int db = 0; db < 4; db++)
                o[db] = __builtin_amdgcn_mfma_f32_16x16x32_bf16(pb, __builtin_bit_cast(bf16x8, bv[c][db]),
                                                                o[db], 0, 0, 0);
            o[4] = __builtin_amdgcn_mfma_f32_16x16x32_bf16(pb, __builtin_bit_cast(bf16x8, ov),
                                                           o[4], 0, 0, 0);
            __builtin_amdgcn_s_setprio(0);
        }
        cur ^= 1;
    }

    // epilogue: broadcast row-sum from col-0 lanes, normalize, store bf16
#pragma unroll
    for (int r = 0; r < 4; r++) {
        float s = __shfl(o[4][r], lane & 48);  // lane quad*16 holds the sum
        float inv = 1.0f / s;
        int n = q0 + quad * 4 + r;
        u16* dst = Out + ((size_t)b * NTOK + n) * DIM + h * HDIM + l16;
#pragma unroll
        for (int db = 0; db < 4; db++)
            dst[db * 16] = f2bf(o[db][r] * inv);
    }
}

// ---------------------------------------------------------------------------
extern "C" void kernel_launch(void* const* d_in, const int* in_sizes, int n_in,
                              void* d_out, int out_size, void* d_ws, size_t ws_size,
                              hipStream_t stream) {
    const float* x = (const float*)d_in[0];
    const float* voxel = (const float*)d_in[1];
    const float* w_qkv = (const float*)d_in[2];
    const float* w_proj = (const float*)d_in[3];
    const float* b_proj = (const float*)d_in[4];
    const float* theta = (const float*)d_in[5];
    const int* gh_p = (const int*)d_in[7];
    const int* gw_p = (const int*)d_in[8];
    const int B = in_sizes[0] / (NTOK * DIM);
    const int M = B * NTOK;

    char* p = (char*)d_ws;
    u16* xb = (u16*)p;       p += (size_t)M * DIM * 2;
    u16* wqkvb = (u16*)p;    p += (size_t)3 * DIM * DIM * 2;
    u16* wprojb = (u16*)p;   p += (size_t)DIM * DIM * 2;
    u16* q_s = (u16*)p;      p += (size_t)M * DIM * 2;
    u16* k_s = (u16*)p;      p += (size_t)M * DIM * 2;
    u16* vT = (u16*)p;       p += (size_t)M * DIM * 2;
    u16* attn = (u16*)p;     p += (size_t)M * DIM * 2;

    int na4 = M * DIM / 4, nb4 = 3 * DIM * DIM / 4, nc4 = DIM * DIM / 4;
    cast3_f32_to_bf16<<<dim3((na4 + nb4 + nc4 + 255) / 256), 256, 0, stream>>>(
        x, xb, na4, w_qkv, wqkvb, nb4, w_proj, wprojb, nc4);

    // QKV GEMM with fused RoPE + flash-layout epilogue: 128x64 tiles, 1152 WG
    gemm_qkv_rope<<<dim3(QKVN / 64, M / 128), 256, 0, stream>>>(
        xb, wqkvb, voxel, theta, gh_p, gw_p, q_s, k_s, vT, M);

    flash_attn<<<dim3((B * NHEADS * NTOK) / 64), 256, 0, stream>>>(q_s, k_s, vT, attn, B * NHEADS);

    // proj GEMM: 64x64 tiles -> 768 WG = 3 WG/CU
    gemm_bt<<<dim3(DIM / 64, M / 64), 256, 0, stream>>>(attn, wprojb, (float*)d_out, b_proj, M, DIM, DIM);
}

// Round 14
// 173.390 us; speedup vs baseline: 1.0416x; 1.0416x over previous
//
#include <hip/hip_runtime.h>
#include <stdint.h>

#define DIM 768
#define NHEADS 12
#define HDIM 64
#define DHALF 32
#define NTOK 2048
#define QKVN 2304
#define LOG2E 1.44269504088896340736f

typedef unsigned short u16;
typedef unsigned int u32;
typedef __bf16 bf16x8 __attribute__((ext_vector_type(8)));
typedef short s16x8 __attribute__((ext_vector_type(8)));
typedef float f32x4 __attribute__((ext_vector_type(4)));

__device__ __forceinline__ f32x4 f4zero() { f32x4 z = {0.f, 0.f, 0.f, 0.f}; return z; }

// fp32 -> bf16 bits, round-to-nearest-even
__device__ __forceinline__ u16 f2bf(float f) {
    u32 u = __builtin_bit_cast(u32, f);
    u32 r = (u + 0x7FFFu + ((u >> 16) & 1u)) >> 16;
    return (u16)r;
}

// async global->LDS, 16B per lane. LDS dest = wave-uniform base + lane*16.
__device__ __forceinline__ void gld_lds16(void* lds, const void* g) {
    __builtin_amdgcn_global_load_lds((const __attribute__((address_space(1))) u32*)g,
                                     (__attribute__((address_space(3))) u32*)lds,
                                     16, 0, 0);
}

// ---------------------------------------------------------------------------
// fused fp32 -> bf16 cast of x, w_qkv, w_proj (one launch)
// ---------------------------------------------------------------------------
__global__ __launch_bounds__(256) void cast3_f32_to_bf16(const float* __restrict__ a, u16* __restrict__ oa, int na4,
                                                         const float* __restrict__ b, u16* __restrict__ ob, int nb4,
                                                         const float* __restrict__ c, u16* __restrict__ oc, int nc4) {
    int i = blockIdx.x * 256 + threadIdx.x;
    const float* src;
    u16* dst;
    int j = i;
    if (i < na4) { src = a; dst = oa; }
    else if (i < na4 + nb4) { src = b; dst = ob; j = i - na4; }
    else if (i < na4 + nb4 + nc4) { src = c; dst = oc; j = i - na4 - nb4; }
    else return;
    float4 v = ((const float4*)src)[j];
    u32 w0 = (u32)f2bf(v.x) | ((u32)f2bf(v.y) << 16);
    u32 w1 = (u32)f2bf(v.z) | ((u32)f2bf(v.w) << 16);
    ((uint2*)dst)[j] = make_uint2(w0, w1);
}

// ---------------------------------------------------------------------------
// proj GEMM 64x64 tiles (768 WG = 3 WG/CU balanced), dbuf gld_lds.
// C[M,N] = A[M,K]*B[N,K]^T (+bias), bf16 in, fp32 out.
// ---------------------------------------------------------------------------
__global__ __launch_bounds__(256) void gemm_bt(const u16* __restrict__ A, const u16* __restrict__ Bm,
                                               float* __restrict__ C, const float* __restrict__ bias,
                                               int M, int N, int K) {
    __shared__ __align__(16) u16 sA[2][64 * 32];
    __shared__ __align__(16) u16 sB[2][64 * 32];
    const int t = threadIdx.x;
    const int wave = t >> 6, lane = t & 63;
    const int quad = lane >> 4, l16 = lane & 15;
    const int bm = blockIdx.y * 64, bn = blockIdx.x * 64;
    const int wr = wave >> 1, wc = wave & 1;

    f32x4 acc[2][2];
#pragma unroll
    for (int i = 0; i < 2; i++)
#pragma unroll
        for (int j = 0; j < 2; j++) acc[i][j] = f4zero();

    auto stage = [&](int k0, int bi) {
        gld_lds16((char*)&sA[bi][0] + wave * 1024,
                  A + (size_t)(bm + wave * 16 + (lane >> 2)) * K + k0 + (lane & 3) * 8);
        gld_lds16((char*)&sB[bi][0] + wave * 1024,
                  Bm + (size_t)(bn + wave * 16 + (lane >> 2)) * K + k0 + (lane & 3) * 8);
    };

    stage(0, 0);
    int cur = 0;
    for (int k0 = 0; k0 < K; k0 += 32) {
        __syncthreads();  // drains DMA of buf[cur]; protects buf[cur^1] reuse
        if (k0 + 32 < K) stage(k0 + 32, cur ^ 1);
        const u16* pA = &sA[cur][0];
        const u16* pB = &sB[cur][0];
        bf16x8 af[2], bfr[2];
#pragma unroll
        for (int mb = 0; mb < 2; mb++)
            af[mb] = *(const bf16x8*)(pA + (wr * 32 + mb * 16 + l16) * 32 + quad * 8);
#pragma unroll
        for (int nb = 0; nb < 2; nb++)
            bfr[nb] = *(const bf16x8*)(pB + (wc * 32 + nb * 16 + l16) * 32 + quad * 8);
#pragma unroll
        for (int mb = 0; mb < 2; mb++)
#pragma unroll
            for (int nb = 0; nb < 2; nb++)
                acc[mb][nb] = __builtin_amdgcn_mfma_f32_16x16x32_bf16(af[mb], bfr[nb], acc[mb][nb], 0, 0, 0);
        cur ^= 1;
    }
#pragma unroll
    for (int mb = 0; mb < 2; mb++)
#pragma unroll
        for (int nb = 0; nb < 2; nb++) {
            int col = bn + wc * 32 + nb * 16 + l16;
            float bv = bias ? bias[col] : 0.f;
#pragma unroll
            for (int r = 0; r < 4; r++) {
                int row = bm + wr * 32 + mb * 16 + quad * 4 + r;
                C[(size_t)row * N + col] = acc[mb][nb][r] + bv;
            }
        }
}

// ---------------------------------------------------------------------------
// QKV-GEMM (fused RoPE + flash-layout epilogue), 128x64 tiles, 4 vertical
// waves, grid 1152 = 4.5 WG/CU. Pow2 fast path for n->(zd,yh,xw).
// ---------------------------------------------------------------------------
__global__ __launch_bounds__(256) void gemm_qkv_rope(const u16* __restrict__ A, const u16* __restrict__ Bm,
                                                     const float* __restrict__ voxel,
                                                     const float* __restrict__ theta,
                                                     const int* __restrict__ gh_p, const int* __restrict__ gw_p,
                                                     u16* __restrict__ q_s, u16* __restrict__ k_s,
                                                     u16* __restrict__ vT, int M) {
    __shared__ __align__(16) u16 sA[2][128 * 32];
    __shared__ __align__(16) u16 sB[2][64 * 32];
    const int t = threadIdx.x;
    const int wave = t >> 6, lane = t & 63;
    const int quad = lane >> 4, l16 = lane & 15;
    const int bm = blockIdx.y * 128, bn = blockIdx.x * 64;
    const int K = DIM;

    f32x4 acc[2][4];
#pragma unroll
    for (int i = 0; i < 2; i++)
#pragma unroll
        for (int j = 0; j < 4; j++) acc[i][j] = f4zero();

    auto stage = [&](int k0, int bi) {
#pragma unroll
        for (int s = 0; s < 2; ++s) {
            int ci = wave * 2 + s;  // A chunk: rows ci*16..ci*16+15
            gld_lds16((char*)&sA[bi][0] + ci * 1024,
                      A + (size_t)(bm + ci * 16 + (lane >> 2)) * K + k0 + (lane & 3) * 8);
        }
        gld_lds16((char*)&sB[bi][0] + wave * 1024,
                  Bm + (size_t)(bn + wave * 16 + (lane >> 2)) * K + k0 + (lane & 3) * 8);
    };

    stage(0, 0);
    int cur = 0;
    for (int k0 = 0; k0 < K; k0 += 32) {
        __syncthreads();
        if (k0 + 32 < K) stage(k0 + 32, cur ^ 1);
        const u16* pA = &sA[cur][0];
        const u16* pB = &sB[cur][0];
        bf16x8 af[2], bfr[4];
#pragma unroll
        for (int mb = 0; mb < 2; mb++)
            af[mb] = *(const bf16x8*)(pA + (wave * 32 + mb * 16 + l16) * 32 + quad * 8);
#pragma unroll
        for (int nb = 0; nb < 4; nb++)
            bfr[nb] = *(const bf16x8*)(pB + (nb * 16 + l16) * 32 + quad * 8);
#pragma unroll
        for (int mb = 0; mb < 2; mb++)
#pragma unroll
            for (int nb = 0; nb < 4; nb++)
                acc[mb][nb] = __builtin_amdgcn_mfma_f32_16x16x32_bf16(af[mb], bfr[nb], acc[mb][nb], 0, 0, 0);
        cur ^= 1;
    }

    // ---------------- fused epilogue ----------------
    const int col0 = bn;                     // 64-col block = one head window
    const int typ = col0 / DIM;              // 0=Q, 1=K, 2=V (block-uniform)
    const int h = (col0 % DIM) >> 6;
    const int b = bm / NTOK;
    const int n0 = (bm % NTOK) + wave * 32;  // wave's token base (mult of 32)
    const size_t bh = (size_t)b * NHEADS + h;

    if (typ == 2) {
        // ---- V: register-local fragment-major pack (one chunk per wave) ----
        int chunk = ((bm % NTOK) >> 5) + wave;
        u16* base = vT + ((size_t)bh * 64 + chunk) * 2048;
#pragma unroll
        for (int nb = 0; nb < 4; nb++) {
            u32 w0 = (u32)f2bf(acc[0][nb][0]) | ((u32)f2bf(acc[0][nb][1]) << 16);
            u32 w1 = (u32)f2bf(acc[0][nb][2]) | ((u32)f2bf(acc[0][nb][3]) << 16);
            u32 w2 = (u32)f2bf(acc[1][nb][0]) | ((u32)f2bf(acc[1][nb][1]) << 16);
            u32 w3 = (u32)f2bf(acc[1][nb][2]) | ((u32)f2bf(acc[1][nb][3]) << 16);
            *(uint4*)(base + nb * 512 + lane * 8) = make_uint4(w0, w1, w2, w3);
        }
    } else {
        // ---- Q/K: in-register RoPE ----
        const int gh = *gh_p, gw = *gw_p;
        const bool p2 = ((gw & (gw - 1)) == 0) && ((gh & (gh - 1)) == 0);
        const int wsh = 31 - __builtin_clz(gw), hsh = 31 - __builtin_clz(gh);
        const float qsc = (typ == 0) ? 0.125f * LOG2E : 1.0f;
        const float th0 = theta[h * DHALF + l16];
        const float th1 = theta[h * DHALF + 16 + l16];
        const int ax0 = l16 % 3, ax1 = (16 + l16) % 3;
        const float vx0 = voxel[ax0], vx1 = voxel[ax1];
#pragma unroll
        for (int mb = 0; mb < 2; mb++)
#pragma unroll
            for (int r = 0; r < 4; r++) {
                int n = n0 + mb * 16 + quad * 4 + r;
                int xw, yh, zd;
                if (p2) {  // pow2 grid (the actual case: 8x16x16): 3 ops
                    xw = n & (gw - 1);
                    int rem = n >> wsh;
                    yh = rem & (gh - 1);
                    zd = rem >> hsh;
                } else {   // generic path, branched around at runtime
                    xw = n % gw;
                    int rem = n / gw;
                    yh = rem % gh;
                    zd = rem / gh;
                }
                float c0 = (float)(ax0 == 0 ? zd : (ax0 == 1 ? yh : xw)) * vx0;
                float c1 = (float)(ax1 == 0 ? zd : (ax1 == 1 ? yh : xw)) * vx1;
                float s0, co0, s1, co1;
                __sincosf(c0 * th0, &s0, &co0);
                __sincosf(c1 * th1, &s1, &co1);
                float t1a = acc[mb][0][r], t2a = acc[mb][2][r];
                float o1a = (t1a * co0 - t2a * s0) * qsc, o2a = (t1a * s0 + t2a * co0) * qsc;
                float t1b = acc[mb][1][r], t2b = acc[mb][3][r];
                float o1b = (t1b * co1 - t2b * s1) * qsc, o2b = (t1b * s1 + t2b * co1) * qsc;
                if (typ == 0) {
                    u16* dq = q_s + (bh * NTOK + n) * HDIM;
                    dq[l16] = f2bf(o1a);
                    dq[l16 + DHALF] = f2bf(o2a);
                    dq[16 + l16] = f2bf(o1b);
                    dq[48 + l16] = f2bf(o2b);
                } else {
                    // fragment-major K (matches flash's kf read pattern)
                    int gm = wave * 2 + mb;
                    int tile_i = ((bm % NTOK) >> 6) + (gm >> 2);
                    int g = gm & 3;
                    int k16 = quad * 4 + r;
                    size_t baseo = bh * (size_t)NTOK * HDIM + (size_t)tile_i * 4096 + g * 1024;
                    int j = l16 & 7;
                    size_t oa = baseo + (size_t)(((l16 >> 3) * 16 + k16) * 8 + j);
                    size_t ob = baseo + (size_t)((((2 + (l16 >> 3)) * 16) + k16) * 8 + j);
                    k_s[oa] = f2bf(o1a);
                    k_s[oa + 512] = f2bf(o2a);
                    k_s[ob] = f2bf(o1b);
                    k_s[ob + 512] = f2bf(o2b);
                }
            }
    }
}

// ---------------------------------------------------------------------------
// Flash attention — FINAL: the R7/R10-measured best (51.1us). 4 waves x 16
// q-rows, grid 768 = 3 WG/CU, frag-major K/V (zero bank conflicts), dbuf
// gld_lds staging, fixed-base softmax, setprio around MFMA clusters (+6.5%
// measured R7). Structural alternatives all measured worse: 2-deep
// c-pipeline null (R8); in-WG split-K +9us (v13: barrier window < DMA
// latency); V-from-L2 +2.5us (v14: in-order vmcnt drains K prefetch);
// V-reg-prefetch +8us (v15: rotation forces pre-barrier vmcnt wait).
// The LDS pipe occupancy (~30us) is overlapped, not binding; the binding
// constraint is the vmcnt/barrier prefetch cadence, which this structure
// already handles optimally at HIP source level.
// ---------------------------------------------------------------------------
__global__ __launch_bounds__(256) void flash_attn(const u16* __restrict__ Q, const u16* __restrict__ Kp,
                                                  const u16* __restrict__ Vp, u16* __restrict__ Out, int NBH) {
    int i = blockIdx.x;
    int bh_i = i % NBH;   // all of a bh's WGs land on XCD bh%8 (24%8==0)
    int qt = i / NBH;     // 0..31
    int b = bh_i / NHEADS, h = bh_i % NHEADS;
    int t = threadIdx.x, wave = t >> 6, lane = t & 63, quad = lane >> 4, l16 = lane & 15;
    size_t bh = (size_t)b * NHEADS + h;
    const u16* Qb = Q + bh * NTOK * HDIM;
    const u16* Kb = Kp + bh * NTOK * HDIM;  // frag-major 4096-elem tiles
    const u16* Vb = Vp + bh * NTOK * HDIM;  // frag-major: 2 chunks x 2048 per tile

    __shared__ __align__(16) u16 smem[2][8192];  // [buf][K 4096 | V 4096] = 32KB

    const int q0 = qt * 64 + wave * 16;  // 16 q-rows per wave
    bf16x8 qf[2];
#pragma unroll
    for (int kc = 0; kc < 2; kc++)
        qf[kc] = *(const bf16x8*)(Qb + (size_t)(q0 + l16) * HDIM + kc * 32 + quad * 8);

    // ones B-frag: col 0 accumulates the P row-sum
    s16x8 ov;
#pragma unroll
    for (int j = 0; j < 8; j++) ov[j] = (l16 == 0) ? (short)0x3F80 : (short)0;

    f32x4 o[5];
#pragma unroll
    for (int db = 0; db < 5; db++) o[db] = f4zero();

    // stage 8KB K + 8KB V of tile kt into buffer bi (4 x 1KB DMA per wave)
    auto stage = [&](int kt, int bi) {
        const u16* Kg = Kb + (size_t)kt * 4096;
        const u16* Vg = Vb + (size_t)kt * 4096;
        u16* buf = &smem[bi][0];
#pragma unroll
        for (int s = 0; s < 2; s++) {
            gld_lds16(buf + (wave * 2 + s) * 512, Kg + (wave * 2 + s) * 512 + lane * 8);
            gld_lds16(buf + 4096 + (wave * 2 + s) * 512, Vg + (wave * 2 + s) * 512 + lane * 8);
        }
    };

    stage(0, 0);
    int cur = 0;
    for (int kt = 0; kt < NTOK / 64; ++kt) {
        __syncthreads();  // drains DMA of buf[cur]; protects buf[cur^1] reuse
        if (kt + 1 < NTOK / 64) stage(kt + 1, cur ^ 1);
        const u16* sK = &smem[cur][0];
        const u16* sV = &smem[cur][4096];
#pragma unroll
        for (int c = 0; c < 2; ++c) {
            bf16x8 kf[2][2];
#pragma unroll
            for (int kb2 = 0; kb2 < 2; kb2++)
#pragma unroll
                for (int kc = 0; kc < 2; kc++)
                    kf[kb2][kc] = *(const bf16x8*)(sK + ((c * 2 + kb2) * 2 + kc) * 512 + lane * 8);
            s16x8 bv[4];
#pragma unroll
            for (int db = 0; db < 4; db++)
                bv[db] = *(const s16x8*)(sV + c * 2048 + db * 512 + lane * 8);
            f32x4 st0, st1;
            __builtin_amdgcn_s_setprio(1);
            {
                f32x4 z = f4zero();
                z = __builtin_amdgcn_mfma_f32_16x16x32_bf16(kf[0][0], qf[0], z, 0, 0, 0);
                st0 = __builtin_amdgcn_mfma_f32_16x16x32_bf16(kf[0][1], qf[1], z, 0, 0, 0);
                f32x4 z2 = f4zero();
                z2 = __builtin_amdgcn_mfma_f32_16x16x32_bf16(kf[1][0], qf[0], z2, 0, 0, 0);
                st1 = __builtin_amdgcn_mfma_f32_16x16x32_bf16(kf[1][1], qf[1], z2, 0, 0, 0);
            }
            __builtin_amdgcn_s_setprio(0);
            bf16x8 pb;
#pragma unroll
            for (int r = 0; r < 4; r++) {
                pb[r] = (__bf16)__builtin_exp2f(st0[r]);
                pb[r + 4] = (__bf16)__builtin_exp2f(st1[r]);
            }
            __builtin_amdgcn_s_setprio(1);
#pragma unroll
            for (int db = 0; db < 4; db++)
                o[db] = __builtin_amdgcn_mfma_f32_16x16x32_bf16(pb, __builtin_bit_cast(bf16x8, bv[db]),
                                                                o[db], 0, 0, 0);
            o[4] = __builtin_amdgcn_mfma_f32_16x16x32_bf16(pb, __builtin_bit_cast(bf16x8, ov),
                                                           o[4], 0, 0, 0);
            __builtin_amdgcn_s_setprio(0);
        }
        cur ^= 1;
    }

    // epilogue: broadcast row-sum from col-0 lanes, normalize, store bf16
#pragma unroll
    for (int r = 0; r < 4; r++) {
        float s = __shfl(o[4][r], lane & 48);  // lane quad*16 holds the sum
        float inv = 1.0f / s;
        int n = q0 + quad * 4 + r;
        u16* dst = Out + ((size_t)b * NTOK + n) * DIM + h * HDIM + l16;
#pragma unroll
        for (int db = 0; db < 4; db++)
            dst[db * 16] = f2bf(o[db][r] * inv);
    }
}

// ---------------------------------------------------------------------------
extern "C" void kernel_launch(void* const* d_in, const int* in_sizes, int n_in,
                              void* d_out, int out_size, void* d_ws, size_t ws_size,
                              hipStream_t stream) {
    const float* x = (const float*)d_in[0];
    const float* voxel = (const float*)d_in[1];
    const float* w_qkv = (const float*)d_in[2];
    const float* w_proj = (const float*)d_in[3];
    const float* b_proj = (const float*)d_in[4];
    const float* theta = (const float*)d_in[5];
    const int* gh_p = (const int*)d_in[7];
    const int* gw_p = (const int*)d_in[8];
    const int B = in_sizes[0] / (NTOK * DIM);
    const int M = B * NTOK;

    char* p = (char*)d_ws;
    u16* xb = (u16*)p;       p += (size_t)M * DIM * 2;
    u16* wqkvb = (u16*)p;    p += (size_t)3 * DIM * DIM * 2;
    u16* wprojb = (u16*)p;   p += (size_t)DIM * DIM * 2;
    u16* q_s = (u16*)p;      p += (size_t)M * DIM * 2;
    u16* k_s = (u16*)p;      p += (size_t)M * DIM * 2;
    u16* vT = (u16*)p;       p += (size_t)M * DIM * 2;
    u16* attn = (u16*)p;     p += (size_t)M * DIM * 2;

    int na4 = M * DIM / 4, nb4 = 3 * DIM * DIM / 4, nc4 = DIM * DIM / 4;
    cast3_f32_to_bf16<<<dim3((na4 + nb4 + nc4 + 255) / 256), 256, 0, stream>>>(
        x, xb, na4, w_qkv, wqkvb, nb4, w_proj, wprojb, nc4);

    // QKV GEMM with fused RoPE + flash-layout epilogue: 128x64 tiles, 1152 WG
    gemm_qkv_rope<<<dim3(QKVN / 64, M / 128), 256, 0, stream>>>(
        xb, wqkvb, voxel, theta, gh_p, gw_p, q_s, k_s, vT, M);

    flash_attn<<<dim3((B * NHEADS * NTOK) / 64), 256, 0, stream>>>(q_s, k_s, vT, attn, B * NHEADS);

    // proj GEMM: 64x64 tiles -> 768 WG = 3 WG/CU
    gemm_bt<<<dim3(DIM / 64, M / 64), 256, 0, stream>>>(attn, wprojb, (float*)d_out, b_proj, M, DIM, DIM);
}